// Round 6
// baseline (243.787 us; speedup 1.0000x reference)
//
#include <hip/hip_runtime.h>
#include <math.h>

#define BGRAPHS 256
#define NNODES  1024
#define CCH     64
#define NEDGE   4194304
#define KKEEP   512

typedef unsigned long long u64;
typedef unsigned int u32;
typedef unsigned short u16;
typedef float  f32x4 __attribute__((ext_vector_type(4)));
typedef int    i32x4 __attribute__((ext_vector_type(4)));

// Output layout (flat float32 elements)
#define OFF_XP   0
#define OFF_EI0  8388608
#define OFF_EI1  (8388608 + NEDGE)
#define OFF_EA   16777216
#define OFF_BP   20971520
#define OFF_SC   21102592
#define OFF_PM   21364736
#define OFF_MSK  21495808

#define FUSED_BLOCKS 1024       // 262144 threads: 16 edges + 8 xp-float4s each
#define GTHREADS     262144

// ---------------- Kernel A: scores (streaming, full occupancy) ----------------
__global__ __launch_bounds__(256) void score_kernel(
    const float* __restrict__ x, const float* __restrict__ w,
    const float* __restrict__ bias, float* __restrict__ sco)
{
    __shared__ float s_w[CCH];
    const int tid = threadIdx.x;
    if (tid < CCH) s_w[tid] = w[tid];
    __syncthreads();

    double n2 = 0.0;
    #pragma unroll
    for (int k = 0; k < CCH; ++k) { double v = (double)s_w[k]; n2 += v * v; }
    const float nrm = (float)sqrt(n2);
    const float bv = bias[0];

    const int node = blockIdx.x * 256 + tid;
    const f32x4* x4 = (const f32x4*)x;
    double acc = 0.0;
    #pragma unroll
    for (int k = 0; k < 16; ++k) {
        f32x4 xv = x4[node * 16 + k];
        acc += (double)xv.x * (double)s_w[4 * k + 0];
        acc += (double)xv.y * (double)s_w[4 * k + 1];
        acc += (double)xv.z * (double)s_w[4 * k + 2];
        acc += (double)xv.w * (double)s_w[4 * k + 3];
    }
    sco[node] = ((float)acc + bv) / nrm;
}

// ---------------- Kernel B: per-graph bitonic top-k (wave-level inner phases) -------
__device__ __forceinline__ u64 cmpex(u64 key, int j, bool dir, int tid) {
    u64 o = (u64)__shfl_xor((long long)key, j, 64);
    bool lower = ((tid & j) == 0);
    u64 mn = key < o ? key : o;
    u64 mx = key < o ? o : key;
    return (dir == lower) ? mn : mx;
}

__global__ __launch_bounds__(1024) void sort_kernel(
    const float* __restrict__ sco, const int* __restrict__ batch,
    float* __restrict__ pmo, float* __restrict__ bpo,
    u16* __restrict__ table16, u16* __restrict__ src16)
{
    __shared__ u64 s_key[NNODES];
    const int b = blockIdx.x;
    const int tid = threadIdx.x;
    const int node = b * NNODES + tid;

    const float score = sco[node];
    // key: descending score (primary), ascending index (secondary) -> ascending u64 sort
    u32 u = __float_as_uint(score);
    u32 mu = u ^ (u32)(((int)u >> 31) | 0x80000000);
    u64 key = ((u64)(~mu) << 32) | (u32)tid;

    // k = 2..64: fully intra-wave (partner = lane ^ j, j <= 32)
    #pragma unroll
    for (int k = 2; k <= 64; k <<= 1) {
        bool dir = ((tid & k) == 0);
        for (int j = k >> 1; j > 0; j >>= 1)
            key = cmpex(key, j, dir, tid);
    }
    s_key[tid] = key;

    // k = 128..1024: LDS steps for j >= 64, then intra-wave tail
    for (int k = 128; k <= NNODES; k <<= 1) {
        bool dir = ((tid & k) == 0);
        for (int j = k >> 1; j >= 64; j >>= 1) {
            __syncthreads();
            int ixj = tid ^ j;
            if (ixj > tid) {
                u64 a = s_key[tid], c = s_key[ixj];
                if ((a > c) == dir) { s_key[tid] = c; s_key[ixj] = a; }
            }
        }
        __syncthreads();
        key = s_key[tid];
        #pragma unroll
        for (int j = 32; j > 0; j >>= 1)
            key = cmpex(key, j, dir, tid);
        s_key[tid] = key;
    }

    const int lidx = (int)(u32)key;
    const int g = b * NNODES + lidx;
    if (tid < KKEEP) {
        pmo[b * KKEEP + tid] = (float)g;
        bpo[b * KKEEP + tid] = (float)batch[g];
        table16[g] = (u16)tid;               // local rank 0..511
        src16[b * KKEEP + tid] = (u16)lidx;  // source local node for gather
    } else {
        table16[g] = 0xFFFFu;
    }
}

// ---------------- Kernel C: uniform fused edge-filter + x_p gather ----------------
// 16 edges + 8 xp-float4s per thread: ~60 independent VMEM ops in flight per
// thread to keep the TCP miss queue full through the scattered table gathers.
__global__ __launch_bounds__(256) void edge_gather_kernel(
    const int* __restrict__ ei, const float* __restrict__ ea,
    const u16* __restrict__ table16,
    const float* __restrict__ x, const u16* __restrict__ src16,
    float* __restrict__ ei0o, float* __restrict__ ei1o,
    float* __restrict__ eao, float* __restrict__ msk,
    float* __restrict__ xp)
{
    const int tid = threadIdx.x;
    const int gt = blockIdx.x * 256 + tid;        // 0..GTHREADS-1
    const int ibase = blockIdx.x * 1024 + tid;    // int4 slot base (4 slots stride 256)

    const i32x4* s4p = (const i32x4*)ei;
    const i32x4* d4p = (const i32x4*)(ei + NEDGE);
    const f32x4* a4p = (const f32x4*)ea;
    const f32x4* x4  = (const f32x4*)x;

    // --- round 1: independent stream loads (12 vec4) + 8 src16 ---
    i32x4 sV[4], dV[4];
    f32x4 aV[4];
    #pragma unroll
    for (int q = 0; q < 4; ++q) sV[q] = __builtin_nontemporal_load(&s4p[ibase + q * 256]);
    #pragma unroll
    for (int q = 0; q < 4; ++q) dV[q] = __builtin_nontemporal_load(&d4p[ibase + q * 256]);
    #pragma unroll
    for (int q = 0; q < 4; ++q) aV[q] = __builtin_nontemporal_load(&a4p[ibase + q * 256]);

    int rowv[8], colv[8], srcv[8];
    #pragma unroll
    for (int p = 0; p < 8; ++p) {
        int elem = gt + p * GTHREADS;
        rowv[p] = elem >> 4;
        colv[p] = elem & 15;
        srcv[p] = (int)src16[rowv[p]];    // 16 lanes share a row -> near-broadcast
    }

    // --- round 2: the 32 scattered table gathers (the critical resource) ---
    u16 vs[4][4], vd[4][4];
    #pragma unroll
    for (int q = 0; q < 4; ++q) {
        #pragma unroll
        for (int e = 0; e < 4; ++e) vs[q][e] = table16[((const int*)&sV[q])[e]];
    }
    #pragma unroll
    for (int q = 0; q < 4; ++q) {
        #pragma unroll
        for (int e = 0; e < 4; ++e) vd[q][e] = table16[((const int*)&dV[q])[e]];
    }

    // --- round 3: x_p source rows (overlap table-gather drain) ---
    f32x4 xv[8];
    #pragma unroll
    for (int p = 0; p < 8; ++p) {
        int b = rowv[p] >> 9;
        xv[p] = x4[((b << 10) + srcv[p]) * 16 + colv[p]];
    }

    // --- compute + stores (edge outputs) ---
    #pragma unroll
    for (int q = 0; q < 4; ++q) {
        f32x4 r4, c4, o4, m4;
        #pragma unroll
        for (int e = 0; e < 4; ++e) {
            int m = (vs[q][e] != 0xFFFFu) && (vd[q][e] != 0xFFFFu);
            int r = ((((const int*)&sV[q])[e] >> 10) << 9) + (int)vs[q][e];
            int c = ((((const int*)&dV[q])[e] >> 10) << 9) + (int)vd[q][e];
            ((float*)&r4)[e] = m ? (float)r : -1.0f;
            ((float*)&c4)[e] = m ? (float)c : -1.0f;
            ((float*)&o4)[e] = m ? ((const float*)&aV[q])[e] : 0.0f;
            ((float*)&m4)[e] = (float)m;
        }
        const int idx = ibase + q * 256;
        __builtin_nontemporal_store(r4, &((f32x4*)ei0o)[idx]);
        __builtin_nontemporal_store(c4, &((f32x4*)ei1o)[idx]);
        __builtin_nontemporal_store(o4, &((f32x4*)eao)[idx]);
        __builtin_nontemporal_store(m4, &((f32x4*)msk)[idx]);
    }

    // --- x_p stores ---
    #pragma unroll
    for (int p = 0; p < 8; ++p)
        __builtin_nontemporal_store(xv[p], &((f32x4*)xp)[gt + p * GTHREADS]);
}

extern "C" void kernel_launch(void* const* d_in, const int* in_sizes, int n_in,
                              void* d_out, int out_size, void* d_ws, size_t ws_size,
                              hipStream_t stream) {
    const float* x          = (const float*)d_in[0];
    const float* w          = (const float*)d_in[1];
    const float* bias       = (const float*)d_in[2];
    const int*   edge_index = (const int*)d_in[3];
    const float* edge_attr  = (const float*)d_in[4];
    const int*   batch      = (const int*)d_in[5];

    float* out = (float*)d_out;
    float* xp   = out + OFF_XP;
    float* ei0o = out + OFF_EI0;
    float* ei1o = out + OFF_EI1;
    float* eao  = out + OFF_EA;
    float* bpo  = out + OFF_BP;
    float* sco  = out + OFF_SC;
    float* pmo  = out + OFF_PM;
    float* msk  = out + OFF_MSK;

    u16* table16 = (u16*)d_ws;                          // B*N u16 = 512 KiB
    u16* src16   = (u16*)d_ws + BGRAPHS * NNODES;       // B*K u16 = 256 KiB

    score_kernel<<<BGRAPHS * NNODES / 256, 256, 0, stream>>>(x, w, bias, sco);
    sort_kernel<<<BGRAPHS, 1024, 0, stream>>>(sco, batch, pmo, bpo, table16, src16);
    edge_gather_kernel<<<FUSED_BLOCKS, 256, 0, stream>>>(
        edge_index, edge_attr, table16, x, src16, ei0o, ei1o, eao, msk, xp);
}